// Round 1
// baseline (905.286 us; speedup 1.0000x reference)
//
#include <hip/hip_runtime.h>

#define H 256
#define NSLOT 4

typedef short bf16x8 __attribute__((ext_vector_type(8)));
typedef float f32x4  __attribute__((ext_vector_type(4)));

__device__ __forceinline__ unsigned int f2bf(float f) {
    unsigned int u = __float_as_uint(f);
    return (u + 0x7fffu + ((u >> 16) & 1u)) >> 16;   // RNE to bf16
}

__global__ void conv_w_kernel(const float* __restrict__ W1, const float* __restrict__ W2,
                              unsigned short* __restrict__ W1b, unsigned short* __restrict__ W2b) {
    int i = blockIdx.x * 256 + threadIdx.x;           // 256 blocks x 256 = 65536
    W1b[i] = (unsigned short)f2bf(W1[i]);
    W2b[i] = (unsigned short)f2bf(W2[i]);
}

// 4 waves/block, 16 rows/wave, 64 rows/block. MFMA 16x16x32 bf16.
// A layout: A[m=lane&15][k=quad*8+j]; B layout: B[k=quad*8+j][n=lane&15];
// C/D: col=lane&15, row=quad*4+reg.   (verified passing earlier)
//
// v2: W fragments are read DIRECTLY from global (W is 128 KB bf16 -> L2/L3
// resident). This deletes the Wl LDS staging buffer and ALL main-loop
// barriers (hlds is wave-private, ordered by the wave's own lgkmcnt).
// LDS 75.8 KB -> 42 KB => 3 blocks/CU. Only 2 __syncthreads remain.
__global__ __launch_bounds__(256, 2) void fused_main(
    const float* __restrict__ x, const int* __restrict__ batch,
    const unsigned short* __restrict__ W1b, const float* __restrict__ b1,
    const unsigned short* __restrict__ W2b, const float* __restrict__ b2,
    float* __restrict__ out, int* __restrict__ counts)
{
    // 264 = 256 + 8 pad shorts -> 528B row stride keeps b128 reads cheap.
    __shared__ __align__(16) unsigned short hlds[4][16][264];   // 33792 B
    __shared__ float        bsum[NSLOT][H];                     // 4096 B
    __shared__ unsigned int bmax[NSLOT][H];                     // 4096 B
    // total 41984 B -> 3 blocks/CU

    const int tid  = threadIdx.x;
    const int wave = tid >> 6;
    const int lane = tid & 63;
    const int r    = lane & 15;   // m / n index
    const int q    = lane >> 4;   // quad
    const int base = blockIdx.x * 64;
    const int r0   = base + wave * 16;

    for (int i = tid; i < NSLOT * H; i += 256) {
        (&bsum[0][0])[i] = 0.0f;
        (&bmax[0][0])[i] = 0u;
    }

    // ---- A1 fragments: x rows, fp32 -> bf16 in regs (32 VGPRs) ----
    bf16x8 a1[8];
    {
        const float* xrow = x + (size_t)(r0 + r) * H;
#pragma unroll
        for (int kk = 0; kk < 8; ++kk) {
            const int k0 = kk * 32 + q * 8;
            const float4 lo = *(const float4*)(xrow + k0);
            const float4 hi = *(const float4*)(xrow + k0 + 4);
            bf16x8 af;
            af[0] = (short)f2bf(lo.x); af[1] = (short)f2bf(lo.y);
            af[2] = (short)f2bf(lo.z); af[3] = (short)f2bf(lo.w);
            af[4] = (short)f2bf(hi.x); af[5] = (short)f2bf(hi.y);
            af[6] = (short)f2bf(hi.z); af[7] = (short)f2bf(hi.w);
            a1[kk] = af;
        }
    }

    // ---- segment bookkeeping (batch sorted) ----
    int sl = batch[base];       sl = sl < 0 ? 0 : (sl > 511 ? 511 : sl);
    int sh = batch[base + 63];  sh = sh < 0 ? 0 : (sh > 511 ? 511 : sh);
    const int  seg_lo     = sl;
    const int  span       = sh - sl + 1;
    const bool small_span = (span >= 1 && span <= NSLOT);
    const bool uni        = (batch[r0] == batch[r0 + 15]);   // wave-uniform
    const int  uslot      = batch[r0] - seg_lo;
    int slot_e[4];
#pragma unroll
    for (int e = 0; e < 4; ++e) slot_e[e] = batch[r0 + q * 4 + e] - seg_lo;

    __syncthreads();   // bsum/bmax init visible before any wave's atomics

    f32x4 hv[16];   // fp32 h kept for the gate (64 VGPRs)

    // ================= GEMM1: h = relu(x @ W1^T + b1) =================
    // B fragment (cg,kk): W1b[(cg*16+r)*256 + kk*32 + q*8], 16B per lane.
#pragma unroll
    for (int cg = 0; cg < 16; ++cg) {
        const bf16x8* wp = (const bf16x8*)(W1b + (size_t)(cg * 16 + r) * H + q * 8);
        f32x4 a = (f32x4){0.f, 0.f, 0.f, 0.f};
#pragma unroll
        for (int kk = 0; kk < 8; ++kk) {
            bf16x8 bfr = wp[kk * 4];   // kk*32 shorts = kk*4 bf16x8
            a = __builtin_amdgcn_mfma_f32_16x16x32_bf16(a1[kk], bfr, a, 0, 0, 0);
        }
        const float bb = b1[cg * 16 + r];
#pragma unroll
        for (int e = 0; e < 4; ++e) {
            float h = a[e] + bb;
            h = h > 0.f ? h : 0.f;
            hv[cg][e] = h;
            hlds[wave][q * 4 + e][cg * 16 + r] = (unsigned short)f2bf(h);
        }
    }

    // ---- A2 fragments from hlds (own wave's 16 rows; wave-private,
    //      ordered by this wave's lgkmcnt -> no barrier needed) ----
    bf16x8 a2[8];
#pragma unroll
    for (int kk = 0; kk < 8; ++kk)
        a2[kk] = *(const bf16x8*)&hlds[wave][r][kk * 32 + q * 8];

    // ========= GEMM2: att = sigmoid(h @ W2^T + b2); g = h*att; reduce =========
#pragma unroll
    for (int cg = 0; cg < 16; ++cg) {
        const bf16x8* wp = (const bf16x8*)(W2b + (size_t)(cg * 16 + r) * H + q * 8);
        f32x4 a = (f32x4){0.f, 0.f, 0.f, 0.f};
#pragma unroll
        for (int kk = 0; kk < 8; ++kk) {
            bf16x8 bfr = wp[kk * 4];
            a = __builtin_amdgcn_mfma_f32_16x16x32_bf16(a2[kk], bfr, a, 0, 0, 0);
        }
        const float bb = b2[cg * 16 + r];
        float g4[4];
#pragma unroll
        for (int e = 0; e < 4; ++e) {
            float t   = a[e] + bb;
            float att = 1.f / (1.f + __expf(-t));
            g4[e] = hv[cg][e] * att;   // g >= 0
        }

        const int col = cg * 16 + r;
        if (small_span) {
            if (uni) {
                float s = g4[0] + g4[1] + g4[2] + g4[3];
                float m = fmaxf(fmaxf(g4[0], g4[1]), fmaxf(g4[2], g4[3]));
                s += __shfl_xor(s, 16, 64);
                s += __shfl_xor(s, 32, 64);
                m = fmaxf(m, __shfl_xor(m, 16, 64));
                m = fmaxf(m, __shfl_xor(m, 32, 64));
                if (q == 0) {
                    atomicAdd(&bsum[uslot][col], s);
                    atomicMax(&bmax[uslot][col], __float_as_uint(m));
                }
            } else {
#pragma unroll
                for (int e = 0; e < 4; ++e) {
                    atomicAdd(&bsum[slot_e[e]][col], g4[e]);
                    atomicMax(&bmax[slot_e[e]][col], __float_as_uint(g4[e]));
                }
            }
        } else {
            // pathological span: direct global atomics
#pragma unroll
            for (int e = 0; e < 4; ++e) {
                int sg = batch[r0 + q * 4 + e];
                sg = sg < 0 ? 0 : (sg > 511 ? 511 : sg);
                atomicAdd(&out[(size_t)sg * 512 + 256 + col], g4[e]);
                atomicMax((unsigned int*)&out[(size_t)sg * 512 + col], __float_as_uint(g4[e]));
            }
        }
    }

    // counts (one per row)
    if (tid < 64) {
        int sg = batch[base + tid];
        sg = sg < 0 ? 0 : (sg > 511 ? 511 : sg);
        atomicAdd(&counts[sg], 1);
    }

    __syncthreads();   // all waves' bsum/bmax atomics complete before drain

    if (small_span) {
        for (int s = 0; s < span; ++s) {
            const int seg = seg_lo + s;
            float        sv = bsum[s][tid];
            unsigned int mv = bmax[s][tid];
            if (sv != 0.0f) atomicAdd(&out[(size_t)seg * 512 + 256 + tid], sv);
            if (mv != 0u)   atomicMax((unsigned int*)&out[(size_t)seg * 512 + tid], mv);
        }
    }
}

__global__ void finalize_kernel(float* __restrict__ out, const int* __restrict__ counts) {
    const int b = blockIdx.x;
    const int c = threadIdx.x;
    const int cnt = counts[b];
    float s = out[(size_t)b * 512 + 256 + c];
    out[(size_t)b * 512 + 256 + c] = cnt > 0 ? s / (float)cnt : 0.0f;
}

extern "C" void kernel_launch(void* const* d_in, const int* in_sizes, int n_in,
                              void* d_out, int out_size, void* d_ws, size_t ws_size,
                              hipStream_t stream) {
    const float* x     = (const float*)d_in[0];
    const int*   batch = (const int*)d_in[1];
    const float* W1    = (const float*)d_in[2];
    const float* b1    = (const float*)d_in[3];
    const float* W2    = (const float*)d_in[4];
    const float* b2    = (const float*)d_in[5];
    float* out = (float*)d_out;

    unsigned short* W1b    = (unsigned short*)d_ws;
    unsigned short* W2b    = W1b + 65536;
    int*            counts = (int*)(W2b + 65536);

    const int Nrows  = in_sizes[0] / H;   // 200000
    const int blocks = Nrows / 64;        // 3125 (exact)

    hipMemsetAsync(d_out, 0, (size_t)out_size * sizeof(float), stream);
    hipMemsetAsync(counts, 0, 512 * sizeof(int), stream);
    conv_w_kernel<<<256, 256, 0, stream>>>(W1, W2, W1b, W2b);
    fused_main<<<blocks, 256, 0, stream>>>(x, batch, W1b, b1, W2b, b2, out, counts);
    finalize_kernel<<<512, 256, 0, stream>>>(out, counts);
}

// Round 2
// 896.275 us; speedup vs baseline: 1.0101x; 1.0101x over previous
//
#include <hip/hip_runtime.h>

#define H 256
#define NSLOT 4

typedef short bf16x8 __attribute__((ext_vector_type(8)));
typedef float f32x4  __attribute__((ext_vector_type(4)));

__device__ __forceinline__ unsigned int f2bf(float f) {
    unsigned int u = __float_as_uint(f);
    return (u + 0x7fffu + ((u >> 16) & 1u)) >> 16;   // RNE to bf16
}

// ======================================================================
// v3 primary path: two persistent-W kernels, barrier-free steady state.
// Block = 1024 threads (16 waves), grid = 256 -> 1 block/CU (LDS 135 KB),
// 4 waves/SIMD. W (bf16) staged to LDS once; each wave then processes
// contiguous 16-row groups with no further synchronization.
// MFMA 16x16x32 bf16. A[m=lane&15][k=q*8+j]; B[k=q*8+j][n=lane&15];
// C/D: col=lane&15, row=q*4+reg (verified layout from earlier rounds).
// LDS row pad: 264 shorts -> 528 B stride -> 16B-slot rotates 1/row ->
// uniform bank use for both b128 stage-writes and b128 fragment reads.
// ======================================================================

__global__ __launch_bounds__(1024, 4) void gemm1_kernel(
    const float* __restrict__ x, const float* __restrict__ W1,
    const float* __restrict__ b1, float* __restrict__ h, int ngroups)
{
    __shared__ __align__(16) unsigned short Wl[256][264];   // 135168 B

    const int tid = threadIdx.x;
    // ---- stage W1 (f32 -> bf16) into LDS, coalesced ----
#pragma unroll
    for (int i = 0; i < 8; ++i) {
        const int c   = tid + i * 1024;        // 8192 chunks of 8 elems
        const int row = c >> 5, col = (c & 31) * 8;
        const float4 lo = *(const float4*)(W1 + row * H + col);
        const float4 hi = *(const float4*)(W1 + row * H + col + 4);
        bf16x8 v;
        v[0] = (short)f2bf(lo.x); v[1] = (short)f2bf(lo.y);
        v[2] = (short)f2bf(lo.z); v[3] = (short)f2bf(lo.w);
        v[4] = (short)f2bf(hi.x); v[5] = (short)f2bf(hi.y);
        v[6] = (short)f2bf(hi.z); v[7] = (short)f2bf(hi.w);
        *(bf16x8*)&Wl[row][col] = v;
    }
    __syncthreads();   // the only barrier in this kernel

    const int wave = tid >> 6, lane = tid & 63;
    const int r = lane & 15, q = lane >> 4;

    float bias[16];
#pragma unroll
    for (int cg = 0; cg < 16; ++cg) bias[cg] = b1[cg * 16 + r];

    // balanced contiguous group range per wave (4096 waves total)
    const int gw = blockIdx.x * 16 + wave;
    const int g0 = (int)(((long long)gw       * ngroups) >> 12);
    const int g1 = (int)(((long long)(gw + 1) * ngroups) >> 12);

    for (int g = g0; g < g1; ++g) {
        const int r0 = g * 16;
        bf16x8 a1[8];
        const float* xrow = x + (size_t)(r0 + r) * H;
#pragma unroll
        for (int kk = 0; kk < 8; ++kk) {
            const int k0 = kk * 32 + q * 8;
            const float4 lo = *(const float4*)(xrow + k0);
            const float4 hi = *(const float4*)(xrow + k0 + 4);
            bf16x8 af;
            af[0] = (short)f2bf(lo.x); af[1] = (short)f2bf(lo.y);
            af[2] = (short)f2bf(lo.z); af[3] = (short)f2bf(lo.w);
            af[4] = (short)f2bf(hi.x); af[5] = (short)f2bf(hi.y);
            af[6] = (short)f2bf(hi.z); af[7] = (short)f2bf(hi.w);
            a1[kk] = af;
        }
#pragma unroll
        for (int cg = 0; cg < 16; ++cg) {
            f32x4 a = (f32x4){0.f, 0.f, 0.f, 0.f};
#pragma unroll
            for (int kk = 0; kk < 8; ++kk) {
                bf16x8 bfr = *(const bf16x8*)&Wl[cg * 16 + r][kk * 32 + q * 8];
                a = __builtin_amdgcn_mfma_f32_16x16x32_bf16(a1[kk], bfr, a, 0, 0, 0);
            }
#pragma unroll
            for (int e = 0; e < 4; ++e) {
                float hv = a[e] + bias[cg];
                hv = hv > 0.f ? hv : 0.f;
                // 4 rows x 64B contiguous per store instr -> coalesced
                h[(size_t)(r0 + q * 4 + e) * H + cg * 16 + r] = hv;
            }
        }
    }
}

__global__ __launch_bounds__(1024, 4) void gemm2_kernel(
    const float* __restrict__ h, const int* __restrict__ batch,
    const float* __restrict__ W2, const float* __restrict__ b2,
    float* __restrict__ out, int* __restrict__ counts, int ngroups)
{
    __shared__ __align__(16) unsigned short Wl[256][264];

    const int tid = threadIdx.x;
#pragma unroll
    for (int i = 0; i < 8; ++i) {
        const int c   = tid + i * 1024;
        const int row = c >> 5, col = (c & 31) * 8;
        const float4 lo = *(const float4*)(W2 + row * H + col);
        const float4 hi = *(const float4*)(W2 + row * H + col + 4);
        bf16x8 v;
        v[0] = (short)f2bf(lo.x); v[1] = (short)f2bf(lo.y);
        v[2] = (short)f2bf(lo.z); v[3] = (short)f2bf(lo.w);
        v[4] = (short)f2bf(hi.x); v[5] = (short)f2bf(hi.y);
        v[6] = (short)f2bf(hi.z); v[7] = (short)f2bf(hi.w);
        *(bf16x8*)&Wl[row][col] = v;
    }
    __syncthreads();   // the only barrier in this kernel

    const int wave = tid >> 6, lane = tid & 63;
    const int r = lane & 15, q = lane >> 4;

    float bias[16];
#pragma unroll
    for (int cg = 0; cg < 16; ++cg) bias[cg] = b2[cg * 16 + r];

    const int gw = blockIdx.x * 16 + wave;
    const int g0 = (int)(((long long)gw       * ngroups) >> 12);
    const int g1 = (int)(((long long)(gw + 1) * ngroups) >> 12);

    for (int g = g0; g < g1; ++g) {
        const int r0 = g * 16;

        // A2 fragments from f32 h rows (same values as bf16(h) before)
        bf16x8 a2[8];
        const float* hrow = h + (size_t)(r0 + r) * H;
#pragma unroll
        for (int kk = 0; kk < 8; ++kk) {
            const int k0 = kk * 32 + q * 8;
            const float4 lo = *(const float4*)(hrow + k0);
            const float4 hi = *(const float4*)(hrow + k0 + 4);
            bf16x8 af;
            af[0] = (short)f2bf(lo.x); af[1] = (short)f2bf(lo.y);
            af[2] = (short)f2bf(lo.z); af[3] = (short)f2bf(lo.w);
            af[4] = (short)f2bf(hi.x); af[5] = (short)f2bf(hi.y);
            af[6] = (short)f2bf(hi.z); af[7] = (short)f2bf(hi.w);
            a2[kk] = af;
        }

        // counts: one add per row
        if (lane < 16) {
            int sg = batch[r0 + lane];
            sg = sg < 0 ? 0 : (sg > 511 ? 511 : sg);
            atomicAdd(&counts[sg], 1);
        }

        int seg_e[4];
#pragma unroll
        for (int e = 0; e < 4; ++e) {
            int sg = batch[r0 + q * 4 + e];
            seg_e[e] = sg < 0 ? 0 : (sg > 511 ? 511 : sg);
        }
        const bool uni = (batch[r0] == batch[r0 + 15]);   // sorted => all equal

#pragma unroll
        for (int cg = 0; cg < 16; ++cg) {
            f32x4 a = (f32x4){0.f, 0.f, 0.f, 0.f};
#pragma unroll
            for (int kk = 0; kk < 8; ++kk) {
                bf16x8 bfr = *(const bf16x8*)&Wl[cg * 16 + r][kk * 32 + q * 8];
                a = __builtin_amdgcn_mfma_f32_16x16x32_bf16(a2[kk], bfr, a, 0, 0, 0);
            }
            const int col = cg * 16 + r;
            float g4[4];
#pragma unroll
            for (int e = 0; e < 4; ++e) {
                float t   = a[e] + bias[cg];
                float att = 1.f / (1.f + __expf(-t));
                // exact f32 h for the gate (L1-hot: row loaded above)
                float hval = h[(size_t)(r0 + q * 4 + e) * H + col];
                g4[e] = hval * att;   // g >= 0
            }
            if (uni) {
                float s = g4[0] + g4[1] + g4[2] + g4[3];
                float m = fmaxf(fmaxf(g4[0], g4[1]), fmaxf(g4[2], g4[3]));
                s += __shfl_xor(s, 16, 64);
                s += __shfl_xor(s, 32, 64);
                m = fmaxf(m, __shfl_xor(m, 16, 64));
                m = fmaxf(m, __shfl_xor(m, 32, 64));
                if (q == 0) {
                    const int seg = seg_e[0];   // == clamp(batch[r0]) on q==0 lanes
                    atomicAdd(&out[(size_t)seg * 512 + 256 + col], s);
                    atomicMax((unsigned int*)&out[(size_t)seg * 512 + col], __float_as_uint(m));
                }
            } else {
#pragma unroll
                for (int e = 0; e < 4; ++e) {
                    atomicAdd(&out[(size_t)seg_e[e] * 512 + 256 + col], g4[e]);
                    atomicMax((unsigned int*)&out[(size_t)seg_e[e] * 512 + col], __float_as_uint(g4[e]));
                }
            }
        }
    }
}

__global__ void finalize_kernel(float* __restrict__ out, const int* __restrict__ counts) {
    const int b = blockIdx.x;
    const int c = threadIdx.x;
    const int cnt = counts[b];
    float s = out[(size_t)b * 512 + 256 + c];
    out[(size_t)b * 512 + 256 + c] = cnt > 0 ? s / (float)cnt : 0.0f;
}

// ======================================================================
// Fallback path (ws too small for the h buffer): previous fused kernel.
// ======================================================================

__global__ void conv_w_kernel(const float* __restrict__ W1, const float* __restrict__ W2,
                              unsigned short* __restrict__ W1b, unsigned short* __restrict__ W2b) {
    int i = blockIdx.x * 256 + threadIdx.x;
    W1b[i] = (unsigned short)f2bf(W1[i]);
    W2b[i] = (unsigned short)f2bf(W2[i]);
}

__global__ __launch_bounds__(256, 2) void fused_main(
    const float* __restrict__ x, const int* __restrict__ batch,
    const unsigned short* __restrict__ W1b, const float* __restrict__ b1,
    const unsigned short* __restrict__ W2b, const float* __restrict__ b2,
    float* __restrict__ out, int* __restrict__ counts)
{
    __shared__ __align__(16) unsigned short hlds[4][16][264];
    __shared__ float        bsum[NSLOT][H];
    __shared__ unsigned int bmax[NSLOT][H];

    const int tid  = threadIdx.x;
    const int wave = tid >> 6;
    const int lane = tid & 63;
    const int r    = lane & 15;
    const int q    = lane >> 4;
    const int base = blockIdx.x * 64;
    const int r0   = base + wave * 16;

    for (int i = tid; i < NSLOT * H; i += 256) {
        (&bsum[0][0])[i] = 0.0f;
        (&bmax[0][0])[i] = 0u;
    }

    bf16x8 a1[8];
    {
        const float* xrow = x + (size_t)(r0 + r) * H;
#pragma unroll
        for (int kk = 0; kk < 8; ++kk) {
            const int k0 = kk * 32 + q * 8;
            const float4 lo = *(const float4*)(xrow + k0);
            const float4 hi = *(const float4*)(xrow + k0 + 4);
            bf16x8 af;
            af[0] = (short)f2bf(lo.x); af[1] = (short)f2bf(lo.y);
            af[2] = (short)f2bf(lo.z); af[3] = (short)f2bf(lo.w);
            af[4] = (short)f2bf(hi.x); af[5] = (short)f2bf(hi.y);
            af[6] = (short)f2bf(hi.z); af[7] = (short)f2bf(hi.w);
            a1[kk] = af;
        }
    }

    int sl = batch[base];       sl = sl < 0 ? 0 : (sl > 511 ? 511 : sl);
    int sh = batch[base + 63];  sh = sh < 0 ? 0 : (sh > 511 ? 511 : sh);
    const int  seg_lo     = sl;
    const int  span       = sh - sl + 1;
    const bool small_span = (span >= 1 && span <= NSLOT);
    const bool uni        = (batch[r0] == batch[r0 + 15]);
    const int  uslot      = batch[r0] - seg_lo;
    int slot_e[4];
#pragma unroll
    for (int e = 0; e < 4; ++e) slot_e[e] = batch[r0 + q * 4 + e] - seg_lo;

    __syncthreads();

    f32x4 hv[16];

#pragma unroll
    for (int cg = 0; cg < 16; ++cg) {
        const bf16x8* wp = (const bf16x8*)(W1b + (size_t)(cg * 16 + r) * H + q * 8);
        f32x4 a = (f32x4){0.f, 0.f, 0.f, 0.f};
#pragma unroll
        for (int kk = 0; kk < 8; ++kk) {
            bf16x8 bfr = wp[kk * 4];
            a = __builtin_amdgcn_mfma_f32_16x16x32_bf16(a1[kk], bfr, a, 0, 0, 0);
        }
        const float bb = b1[cg * 16 + r];
#pragma unroll
        for (int e = 0; e < 4; ++e) {
            float h = a[e] + bb;
            h = h > 0.f ? h : 0.f;
            hv[cg][e] = h;
            hlds[wave][q * 4 + e][cg * 16 + r] = (unsigned short)f2bf(h);
        }
    }

    bf16x8 a2[8];
#pragma unroll
    for (int kk = 0; kk < 8; ++kk)
        a2[kk] = *(const bf16x8*)&hlds[wave][r][kk * 32 + q * 8];

#pragma unroll
    for (int cg = 0; cg < 16; ++cg) {
        const bf16x8* wp = (const bf16x8*)(W2b + (size_t)(cg * 16 + r) * H + q * 8);
        f32x4 a = (f32x4){0.f, 0.f, 0.f, 0.f};
#pragma unroll
        for (int kk = 0; kk < 8; ++kk) {
            bf16x8 bfr = wp[kk * 4];
            a = __builtin_amdgcn_mfma_f32_16x16x32_bf16(a2[kk], bfr, a, 0, 0, 0);
        }
        const float bb = b2[cg * 16 + r];
        float g4[4];
#pragma unroll
        for (int e = 0; e < 4; ++e) {
            float t   = a[e] + bb;
            float att = 1.f / (1.f + __expf(-t));
            g4[e] = hv[cg][e] * att;
        }

        const int col = cg * 16 + r;
        if (small_span) {
            if (uni) {
                float s = g4[0] + g4[1] + g4[2] + g4[3];
                float m = fmaxf(fmaxf(g4[0], g4[1]), fmaxf(g4[2], g4[3]));
                s += __shfl_xor(s, 16, 64);
                s += __shfl_xor(s, 32, 64);
                m = fmaxf(m, __shfl_xor(m, 16, 64));
                m = fmaxf(m, __shfl_xor(m, 32, 64));
                if (q == 0) {
                    atomicAdd(&bsum[uslot][col], s);
                    atomicMax(&bmax[uslot][col], __float_as_uint(m));
                }
            } else {
#pragma unroll
                for (int e = 0; e < 4; ++e) {
                    atomicAdd(&bsum[slot_e[e]][col], g4[e]);
                    atomicMax(&bmax[slot_e[e]][col], __float_as_uint(g4[e]));
                }
            }
        } else {
#pragma unroll
            for (int e = 0; e < 4; ++e) {
                int sg = batch[r0 + q * 4 + e];
                sg = sg < 0 ? 0 : (sg > 511 ? 511 : sg);
                atomicAdd(&out[(size_t)sg * 512 + 256 + col], g4[e]);
                atomicMax((unsigned int*)&out[(size_t)sg * 512 + col], __float_as_uint(g4[e]));
            }
        }
    }

    if (tid < 64) {
        int sg = batch[base + tid];
        sg = sg < 0 ? 0 : (sg > 511 ? 511 : sg);
        atomicAdd(&counts[sg], 1);
    }

    __syncthreads();

    if (small_span) {
        for (int s = 0; s < span; ++s) {
            const int seg = seg_lo + s;
            float        sv = bsum[s][tid];
            unsigned int mv = bmax[s][tid];
            if (sv != 0.0f) atomicAdd(&out[(size_t)seg * 512 + 256 + tid], sv);
            if (mv != 0u)   atomicMax((unsigned int*)&out[(size_t)seg * 512 + tid], mv);
        }
    }
}

extern "C" void kernel_launch(void* const* d_in, const int* in_sizes, int n_in,
                              void* d_out, int out_size, void* d_ws, size_t ws_size,
                              hipStream_t stream) {
    const float* x     = (const float*)d_in[0];
    const int*   batch = (const int*)d_in[1];
    const float* W1    = (const float*)d_in[2];
    const float* b1    = (const float*)d_in[3];
    const float* W2    = (const float*)d_in[4];
    const float* b2    = (const float*)d_in[5];
    float* out = (float*)d_out;

    const int Nrows = in_sizes[0] / H;          // 200000
    const size_t hbytes = (size_t)Nrows * H * sizeof(float);   // ~204.8 MB

    if (ws_size >= hbytes + 4096) {
        // ---- primary path: two persistent-W kernels via f32 h buffer ----
        float* hbuf   = (float*)d_ws;
        int*   counts = (int*)((char*)d_ws + hbytes);
        const int ngroups = Nrows / 16;         // 12500

        hipMemsetAsync(d_out, 0, (size_t)out_size * sizeof(float), stream);
        hipMemsetAsync(counts, 0, 512 * sizeof(int), stream);
        gemm1_kernel<<<256, 1024, 0, stream>>>(x, W1, b1, hbuf, ngroups);
        gemm2_kernel<<<256, 1024, 0, stream>>>(hbuf, batch, W2, b2, out, counts, ngroups);
        finalize_kernel<<<512, 256, 0, stream>>>(out, counts);
    } else {
        // ---- fallback: previous fused kernel (small workspace) ----
        unsigned short* W1b    = (unsigned short*)d_ws;
        unsigned short* W2b    = W1b + 65536;
        int*            counts = (int*)(W2b + 65536);
        const int blocks = Nrows / 64;

        hipMemsetAsync(d_out, 0, (size_t)out_size * sizeof(float), stream);
        hipMemsetAsync(counts, 0, 512 * sizeof(int), stream);
        conv_w_kernel<<<256, 256, 0, stream>>>(W1, W2, W1b, W2b);
        fused_main<<<blocks, 256, 0, stream>>>(x, batch, W1b, b1, W2b, b2, out, counts);
        finalize_kernel<<<512, 256, 0, stream>>>(out, counts);
    }
}

// Round 3
// 825.672 us; speedup vs baseline: 1.0964x; 1.0855x over previous
//
#include <hip/hip_runtime.h>

#define H 256
#define NSLOT 4

typedef short bf16x8 __attribute__((ext_vector_type(8)));
typedef float f32x4  __attribute__((ext_vector_type(4)));

__device__ __forceinline__ unsigned int f2bf(float f) {
    unsigned int u = __float_as_uint(f);
    return (u + 0x7fffu + ((u >> 16) & 1u)) >> 16;   // RNE to bf16
}

__global__ void conv_w_kernel(const float* __restrict__ W1, const float* __restrict__ W2,
                              unsigned short* __restrict__ W1b, unsigned short* __restrict__ W2b) {
    int i = blockIdx.x * 256 + threadIdx.x;           // 256 x 256 = 65536
    W1b[i] = (unsigned short)f2bf(W1[i]);
    W2b[i] = (unsigned short)f2bf(W2[i]);
}

// ======================================================================
// v4: two persistent-W kernels; h round-trips in gemm1's C/D emission
// order so every global access on the h path is full-line coalesced.
//   h index: g*4096 + (cg*4+e)*64 + lane   (lane = q*16+r)
//   element: h[row g*16 + q*4+e][col cg*16+r]
// MFMA 16x16x32 bf16. A[m=lane&15][k=q*8+j]; B[k=q*8+j][n=lane&15];
// C/D: col=lane&15, row=q*4+e (layout verified in earlier rounds).
// ======================================================================

__global__ __launch_bounds__(1024, 4) void gemm1_kernel(
    const float* __restrict__ x, const unsigned short* __restrict__ W1b,
    const float* __restrict__ b1, float* __restrict__ hbuf, int ngroups)
{
    __shared__ __align__(16) unsigned short Wl[256][264];   // 135168 B

    const int tid = threadIdx.x;
#pragma unroll
    for (int i = 0; i < 8; ++i) {
        const int c = tid + (i << 10);                 // 8192 bf16x8 chunks
        *(bf16x8*)&Wl[c >> 5][(c & 31) * 8] = *(const bf16x8*)(W1b + c * 8);
    }
    __syncthreads();   // the only barrier

    const int wave = tid >> 6, lane = tid & 63;
    const int r = lane & 15, q = lane >> 4;

    float bias[16];
#pragma unroll
    for (int cg = 0; cg < 16; ++cg) bias[cg] = b1[cg * 16 + r];

    const int gw = blockIdx.x * 16 + wave;             // 4096 waves
    const int g0 = (int)(((long long)gw       * ngroups) >> 12);
    const int g1 = (int)(((long long)(gw + 1) * ngroups) >> 12);

    for (int g = g0; g < g1; ++g) {
        bf16x8 a1[8];
        const float* xrow = x + (size_t)(g * 16 + r) * H + q * 8;
#pragma unroll
        for (int kk = 0; kk < 8; ++kk) {
            const float4 lo = *(const float4*)(xrow + kk * 32);
            const float4 hi = *(const float4*)(xrow + kk * 32 + 4);
            bf16x8 af;
            af[0] = (short)f2bf(lo.x); af[1] = (short)f2bf(lo.y);
            af[2] = (short)f2bf(lo.z); af[3] = (short)f2bf(lo.w);
            af[4] = (short)f2bf(hi.x); af[5] = (short)f2bf(hi.y);
            af[6] = (short)f2bf(hi.z); af[7] = (short)f2bf(hi.w);
            a1[kk] = af;
        }
        float* hg = hbuf + (size_t)g * 4096;
#pragma unroll
        for (int cg = 0; cg < 16; ++cg) {
            f32x4 a = (f32x4){0.f, 0.f, 0.f, 0.f};
#pragma unroll
            for (int kk = 0; kk < 8; ++kk) {
                bf16x8 bfr = *(const bf16x8*)&Wl[cg * 16 + r][kk * 32 + q * 8];
                a = __builtin_amdgcn_mfma_f32_16x16x32_bf16(a1[kk], bfr, a, 0, 0, 0);
            }
#pragma unroll
            for (int e = 0; e < 4; ++e) {
                float v = a[e] + bias[cg];
                v = v > 0.f ? v : 0.f;
                hg[(cg * 4 + e) * 64 + lane] = v;      // 256B contiguous per instr
            }
        }
    }
}

__global__ __launch_bounds__(1024, 4) void gemm2_kernel(
    const float* __restrict__ hbuf, const int* __restrict__ batch,
    const unsigned short* __restrict__ W2b, const float* __restrict__ b2,
    float* __restrict__ out, int* __restrict__ counts, int ngroups)
{
    __shared__ __align__(16) unsigned short Wl[256][264];   // 135168 B
    __shared__ float        bsum[8][H];                     // 8192 B
    __shared__ unsigned int bmax[8][H];                     // 8192 B
    // total 151552 B <= 160 KiB -> 1 block/CU, 16 waves

    const int tid = threadIdx.x;
#pragma unroll
    for (int i = 0; i < 8; ++i) {
        const int c = tid + (i << 10);
        *(bf16x8*)&Wl[c >> 5][(c & 31) * 8] = *(const bf16x8*)(W2b + c * 8);
    }
    for (int i = tid; i < 8 * H; i += 1024) {
        (&bsum[0][0])[i] = 0.0f;
        (&bmax[0][0])[i] = 0u;
    }
    __syncthreads();

    const int wave = tid >> 6, lane = tid & 63;
    const int r = lane & 15, q = lane >> 4;

    float bias[16];
#pragma unroll
    for (int cg = 0; cg < 16; ++cg) bias[cg] = b2[cg * 16 + r];

    // block-level segment window (batch sorted; block covers rows [bg0*16, bg1*16))
    const int bid = blockIdx.x;
    const int bg0 = (int)(((long long)(bid * 16)      * ngroups) >> 12);
    const int bg1 = (int)(((long long)(bid * 16 + 16) * ngroups) >> 12);
    int s_lo = batch[bg0 * 16];      s_lo = s_lo < 0 ? 0 : (s_lo > 511 ? 511 : s_lo);
    int s_hi = batch[bg1 * 16 - 1];  s_hi = s_hi < 0 ? 0 : (s_hi > 511 ? 511 : s_hi);
    const int  span    = s_hi - s_lo + 1;
    const bool use_lds = (span >= 1 && span <= 8);

    const int gw = bid * 16 + wave;
    const int g0 = (int)(((long long)gw       * ngroups) >> 12);
    const int g1 = (int)(((long long)(gw + 1) * ngroups) >> 12);

    // per-lane A-fragment base offset within a 4096-float h group block:
    // h[row r][col 32kk+q*8+j] = hg[fo + kk*512 + j], j=0..7 contiguous
    const int fo = (q >> 1) * 256 + (r & 3) * 64 + (r >> 2) * 16 + (q & 1) * 8;

    for (int g = g0; g < g1; ++g) {
        const float* hg = hbuf + (size_t)g * 4096;
        bf16x8 a2[8];
#pragma unroll
        for (int kk = 0; kk < 8; ++kk) {
            const float4 lo = *(const float4*)(hg + fo + kk * 512);
            const float4 hi = *(const float4*)(hg + fo + kk * 512 + 4);
            bf16x8 af;
            af[0] = (short)f2bf(lo.x); af[1] = (short)f2bf(lo.y);
            af[2] = (short)f2bf(lo.z); af[3] = (short)f2bf(lo.w);
            af[4] = (short)f2bf(hi.x); af[5] = (short)f2bf(hi.y);
            af[6] = (short)f2bf(hi.z); af[7] = (short)f2bf(hi.w);
            a2[kk] = af;
        }

        const int r0 = g * 16;
        if (lane < 16) {
            int sg = batch[r0 + lane];
            sg = sg < 0 ? 0 : (sg > 511 ? 511 : sg);
            atomicAdd(&counts[sg], 1);
        }
        int seg_e[4];
#pragma unroll
        for (int e = 0; e < 4; ++e) {
            int sg = batch[r0 + q * 4 + e];
            seg_e[e] = sg < 0 ? 0 : (sg > 511 ? 511 : sg);
        }
        const bool uni = (batch[r0] == batch[r0 + 15]);

#pragma unroll
        for (int cg = 0; cg < 16; ++cg) {
            f32x4 a = (f32x4){0.f, 0.f, 0.f, 0.f};
#pragma unroll
            for (int kk = 0; kk < 8; ++kk) {
                bf16x8 bfr = *(const bf16x8*)&Wl[cg * 16 + r][kk * 32 + q * 8];
                a = __builtin_amdgcn_mfma_f32_16x16x32_bf16(a2[kk], bfr, a, 0, 0, 0);
            }
            float g4[4];
#pragma unroll
            for (int e = 0; e < 4; ++e) {
                float t   = a[e] + bias[cg];
                float att = 1.f / (1.f + __expf(-t));
                // exact f32 h for the gate; coalesced 256B re-read, lines hot
                float hval = hg[(cg * 4 + e) * 64 + lane];
                g4[e] = hval * att;   // g >= 0
            }
            const int col = cg * 16 + r;
            if (use_lds) {
                if (uni) {
                    float s = g4[0] + g4[1] + g4[2] + g4[3];
                    float m = fmaxf(fmaxf(g4[0], g4[1]), fmaxf(g4[2], g4[3]));
                    s += __shfl_xor(s, 16, 64);
                    s += __shfl_xor(s, 32, 64);
                    m = fmaxf(m, __shfl_xor(m, 16, 64));
                    m = fmaxf(m, __shfl_xor(m, 32, 64));
                    if (q == 0) {
                        const int sl = seg_e[0] - s_lo;   // batch[r0] on q==0 lanes
                        atomicAdd(&bsum[sl][col], s);
                        atomicMax(&bmax[sl][col], __float_as_uint(m));
                    }
                } else {
#pragma unroll
                    for (int e = 0; e < 4; ++e) {
                        const int sl = seg_e[e] - s_lo;
                        atomicAdd(&bsum[sl][col], g4[e]);
                        atomicMax(&bmax[sl][col], __float_as_uint(g4[e]));
                    }
                }
            } else {
                // pathological span: direct global atomics
#pragma unroll
                for (int e = 0; e < 4; ++e) {
                    atomicAdd(&out[(size_t)seg_e[e] * 512 + 256 + col], g4[e]);
                    atomicMax((unsigned int*)&out[(size_t)seg_e[e] * 512 + col], __float_as_uint(g4[e]));
                }
            }
        }
    }

    __syncthreads();   // all waves' LDS atomics done before drain

    if (use_lds && tid < H) {
        for (int s = 0; s < span; ++s) {
            const int seg = s_lo + s;
            float        sv = bsum[s][tid];
            unsigned int mv = bmax[s][tid];
            if (sv != 0.0f) atomicAdd(&out[(size_t)seg * 512 + 256 + tid], sv);
            if (mv != 0u)   atomicMax((unsigned int*)&out[(size_t)seg * 512 + tid], mv);
        }
    }
}

__global__ void finalize_kernel(float* __restrict__ out, const int* __restrict__ counts) {
    const int b = blockIdx.x;
    const int c = threadIdx.x;
    const int cnt = counts[b];
    float s = out[(size_t)b * 512 + 256 + c];
    out[(size_t)b * 512 + 256 + c] = cnt > 0 ? s / (float)cnt : 0.0f;
}

// ======================================================================
// Fallback path (ws too small for the h buffer): fused kernel (v1).
// ======================================================================

__global__ __launch_bounds__(256, 2) void fused_main(
    const float* __restrict__ x, const int* __restrict__ batch,
    const unsigned short* __restrict__ W1b, const float* __restrict__ b1,
    const unsigned short* __restrict__ W2b, const float* __restrict__ b2,
    float* __restrict__ out, int* __restrict__ counts)
{
    __shared__ __align__(16) unsigned short hlds[4][16][264];
    __shared__ float        bsum[NSLOT][H];
    __shared__ unsigned int bmax[NSLOT][H];

    const int tid  = threadIdx.x;
    const int wave = tid >> 6;
    const int lane = tid & 63;
    const int r    = lane & 15;
    const int q    = lane >> 4;
    const int base = blockIdx.x * 64;
    const int r0   = base + wave * 16;

    for (int i = tid; i < NSLOT * H; i += 256) {
        (&bsum[0][0])[i] = 0.0f;
        (&bmax[0][0])[i] = 0u;
    }

    bf16x8 a1[8];
    {
        const float* xrow = x + (size_t)(r0 + r) * H;
#pragma unroll
        for (int kk = 0; kk < 8; ++kk) {
            const int k0 = kk * 32 + q * 8;
            const float4 lo = *(const float4*)(xrow + k0);
            const float4 hi = *(const float4*)(xrow + k0 + 4);
            bf16x8 af;
            af[0] = (short)f2bf(lo.x); af[1] = (short)f2bf(lo.y);
            af[2] = (short)f2bf(lo.z); af[3] = (short)f2bf(lo.w);
            af[4] = (short)f2bf(hi.x); af[5] = (short)f2bf(hi.y);
            af[6] = (short)f2bf(hi.z); af[7] = (short)f2bf(hi.w);
            a1[kk] = af;
        }
    }

    int sl = batch[base];       sl = sl < 0 ? 0 : (sl > 511 ? 511 : sl);
    int sh = batch[base + 63];  sh = sh < 0 ? 0 : (sh > 511 ? 511 : sh);
    const int  seg_lo     = sl;
    const int  span       = sh - sl + 1;
    const bool small_span = (span >= 1 && span <= NSLOT);
    const bool uni        = (batch[r0] == batch[r0 + 15]);
    const int  uslot      = batch[r0] - seg_lo;
    int slot_e[4];
#pragma unroll
    for (int e = 0; e < 4; ++e) slot_e[e] = batch[r0 + q * 4 + e] - seg_lo;

    __syncthreads();

    f32x4 hv[16];

#pragma unroll
    for (int cg = 0; cg < 16; ++cg) {
        const bf16x8* wp = (const bf16x8*)(W1b + (size_t)(cg * 16 + r) * H + q * 8);
        f32x4 a = (f32x4){0.f, 0.f, 0.f, 0.f};
#pragma unroll
        for (int kk = 0; kk < 8; ++kk) {
            bf16x8 bfr = wp[kk * 4];
            a = __builtin_amdgcn_mfma_f32_16x16x32_bf16(a1[kk], bfr, a, 0, 0, 0);
        }
        const float bb = b1[cg * 16 + r];
#pragma unroll
        for (int e = 0; e < 4; ++e) {
            float h = a[e] + bb;
            h = h > 0.f ? h : 0.f;
            hv[cg][e] = h;
            hlds[wave][q * 4 + e][cg * 16 + r] = (unsigned short)f2bf(h);
        }
    }

    bf16x8 a2[8];
#pragma unroll
    for (int kk = 0; kk < 8; ++kk)
        a2[kk] = *(const bf16x8*)&hlds[wave][r][kk * 32 + q * 8];

#pragma unroll
    for (int cg = 0; cg < 16; ++cg) {
        const bf16x8* wp = (const bf16x8*)(W2b + (size_t)(cg * 16 + r) * H + q * 8);
        f32x4 a = (f32x4){0.f, 0.f, 0.f, 0.f};
#pragma unroll
        for (int kk = 0; kk < 8; ++kk) {
            bf16x8 bfr = wp[kk * 4];
            a = __builtin_amdgcn_mfma_f32_16x16x32_bf16(a2[kk], bfr, a, 0, 0, 0);
        }
        const float bb = b2[cg * 16 + r];
        float g4[4];
#pragma unroll
        for (int e = 0; e < 4; ++e) {
            float t   = a[e] + bb;
            float att = 1.f / (1.f + __expf(-t));
            g4[e] = hv[cg][e] * att;
        }

        const int col = cg * 16 + r;
        if (small_span) {
            if (uni) {
                float s = g4[0] + g4[1] + g4[2] + g4[3];
                float m = fmaxf(fmaxf(g4[0], g4[1]), fmaxf(g4[2], g4[3]));
                s += __shfl_xor(s, 16, 64);
                s += __shfl_xor(s, 32, 64);
                m = fmaxf(m, __shfl_xor(m, 16, 64));
                m = fmaxf(m, __shfl_xor(m, 32, 64));
                if (q == 0) {
                    atomicAdd(&bsum[uslot][col], s);
                    atomicMax(&bmax[uslot][col], __float_as_uint(m));
                }
            } else {
#pragma unroll
                for (int e = 0; e < 4; ++e) {
                    atomicAdd(&bsum[slot_e[e]][col], g4[e]);
                    atomicMax(&bmax[slot_e[e]][col], __float_as_uint(g4[e]));
                }
            }
        } else {
#pragma unroll
            for (int e = 0; e < 4; ++e) {
                int sg = batch[r0 + q * 4 + e];
                sg = sg < 0 ? 0 : (sg > 511 ? 511 : sg);
                atomicAdd(&out[(size_t)sg * 512 + 256 + col], g4[e]);
                atomicMax((unsigned int*)&out[(size_t)sg * 512 + col], __float_as_uint(g4[e]));
            }
        }
    }

    if (tid < 64) {
        int sg = batch[base + tid];
        sg = sg < 0 ? 0 : (sg > 511 ? 511 : sg);
        atomicAdd(&counts[sg], 1);
    }

    __syncthreads();

    if (small_span) {
        for (int s = 0; s < span; ++s) {
            const int seg = seg_lo + s;
            float        sv = bsum[s][tid];
            unsigned int mv = bmax[s][tid];
            if (sv != 0.0f) atomicAdd(&out[(size_t)seg * 512 + 256 + tid], sv);
            if (mv != 0u)   atomicMax((unsigned int*)&out[(size_t)seg * 512 + tid], mv);
        }
    }
}

extern "C" void kernel_launch(void* const* d_in, const int* in_sizes, int n_in,
                              void* d_out, int out_size, void* d_ws, size_t ws_size,
                              hipStream_t stream) {
    const float* x     = (const float*)d_in[0];
    const int*   batch = (const int*)d_in[1];
    const float* W1    = (const float*)d_in[2];
    const float* b1    = (const float*)d_in[3];
    const float* W2    = (const float*)d_in[4];
    const float* b2    = (const float*)d_in[5];
    float* out = (float*)d_out;

    const int Nrows = in_sizes[0] / H;                         // 200000
    const size_t hbytes = (size_t)Nrows * H * sizeof(float);   // ~204.8 MB

    if (ws_size >= hbytes + 2 * 65536 * sizeof(unsigned short) + 4096) {
        // ---- primary: persistent-W kernels, coalesced h round-trip ----
        float*          hbuf   = (float*)d_ws;
        unsigned short* W1b    = (unsigned short*)((char*)d_ws + hbytes);
        unsigned short* W2b    = W1b + 65536;
        int*            counts = (int*)(W2b + 65536);
        const int ngroups = Nrows / 16;                        // 12500

        hipMemsetAsync(d_out, 0, (size_t)out_size * sizeof(float), stream);
        hipMemsetAsync(counts, 0, 512 * sizeof(int), stream);
        conv_w_kernel<<<256, 256, 0, stream>>>(W1, W2, W1b, W2b);
        gemm1_kernel<<<256, 1024, 0, stream>>>(x, W1b, b1, hbuf, ngroups);
        gemm2_kernel<<<256, 1024, 0, stream>>>(hbuf, batch, W2b, b2, out, counts, ngroups);
        finalize_kernel<<<512, 256, 0, stream>>>(out, counts);
    } else {
        // ---- fallback: fused kernel (small workspace) ----
        unsigned short* W1b    = (unsigned short*)d_ws;
        unsigned short* W2b    = W1b + 65536;
        int*            counts = (int*)(W2b + 65536);
        const int blocks = Nrows / 64;

        hipMemsetAsync(d_out, 0, (size_t)out_size * sizeof(float), stream);
        hipMemsetAsync(counts, 0, 512 * sizeof(int), stream);
        conv_w_kernel<<<256, 256, 0, stream>>>(W1, W2, W1b, W2b);
        fused_main<<<blocks, 256, 0, stream>>>(x, batch, W1b, b1, W2b, b2, out, counts);
        finalize_kernel<<<512, 256, 0, stream>>>(out, counts);
    }
}

// Round 4
// 393.249 us; speedup vs baseline: 2.3021x; 2.0996x over previous
//
#include <hip/hip_runtime.h>

#define H 256

typedef short bf16x8 __attribute__((ext_vector_type(8)));
typedef float f32x4  __attribute__((ext_vector_type(4)));

__device__ __forceinline__ unsigned int f2bf(float f) {
    unsigned int u = __float_as_uint(f);
    return (u + 0x7fffu + ((u >> 16) & 1u)) >> 16;   // RNE to bf16
}
__device__ __forceinline__ int clampseg(int s) { return s < 0 ? 0 : (s > 511 ? 511 : s); }

__global__ void conv_w_kernel(const float* __restrict__ W1, const float* __restrict__ W2,
                              unsigned short* __restrict__ W1b, unsigned short* __restrict__ W2b) {
    int i = blockIdx.x * 256 + threadIdx.x;           // 256 x 256 = 65536
    W1b[i] = (unsigned short)f2bf(W1[i]);
    W2b[i] = (unsigned short)f2bf(W2[i]);
}

// ======================================================================
// v5: single fused kernel, column-sliced weights in registers.
//  - 256 blocks x 1024 threads (16 waves). Wave w owns output cols
//    [w*16, w*16+16) for BOTH GEMMs -> needs only 16 W-rows (8 KB bf16,
//    L1-hot, reloaded per chunk into 32 VGPRs). No W in LDS, no h in
//    global: h crosses waves through a 64x256 bf16 LDS tile per chunk.
//  - x staged to LDS bf16, double-buffered; next-chunk loads issued
//    before GEMM1 so HBM latency hides under compute.
//  - 2 barriers per 64-row chunk (~26 per block lifetime).
//  - Segment reduction: per-wave 4-slot sliding window in registers
//    (static-indexed), quad-combine via shfl, one atomic pair per
//    (wave, segment); direct-atomic fallback for out-of-window rows.
// MFMA 16x16x32 bf16. A[m=lane&15][k=q*8+j]; B[k=q*8+j][n=lane&15];
// C/D: col=lane&15, row=q*4+e (layout verified in earlier rounds).
// LDS: xl dbuf 2x33792 + hl 33792 = 101376 B -> 1 block/CU, 16 waves.
// ======================================================================
__global__ __launch_bounds__(1024, 4) void fused_v5(
    const float* __restrict__ x, const int* __restrict__ batch,
    const unsigned short* __restrict__ W1b, const float* __restrict__ b1,
    const unsigned short* __restrict__ W2b, const float* __restrict__ b2,
    float* __restrict__ out, int* __restrict__ counts, int nchunks)
{
    __shared__ __align__(16) unsigned short xl[2][64][264];   // 2 x 33792 B
    __shared__ __align__(16) unsigned short hl[64][264];      // 33792 B

    const int tid  = threadIdx.x;
    const int wave = tid >> 6, lane = tid & 63;
    const int r = lane & 15, q = lane >> 4;
    const int col = wave * 16 + r;        // this lane's output column

    const int b  = blockIdx.x;
    const int c0 = (int)(((long long)b       * nchunks) >> 8);
    const int c1 = (int)(((long long)(b + 1) * nchunks) >> 8);
    if (c0 >= c1) return;

    const float bias1 = b1[col];
    const float bias2 = b2[col];

    // per-wave segment window state (per-lane accumulators, col fixed)
    float accs[4] = {0.f, 0.f, 0.f, 0.f};
    float accm[4] = {0.f, 0.f, 0.f, 0.f};
    int wb = clampseg(batch[c0 * 64]);

#define FLUSH_SLOTS()                                                              \
    do {                                                                           \
        _Pragma("unroll")                                                          \
        for (int s = 0; s < 4; ++s) {                                              \
            float sv = accs[s];                                                    \
            float mv = accm[s];                                                    \
            sv += __shfl_xor(sv, 16, 64);                                          \
            sv += __shfl_xor(sv, 32, 64);                                          \
            mv = fmaxf(mv, __shfl_xor(mv, 16, 64));                                \
            mv = fmaxf(mv, __shfl_xor(mv, 32, 64));                                \
            if (q == 0 && (sv != 0.f || mv != 0.f)) {                              \
                const int seg = clampseg(wb + s);                                  \
                atomicAdd(&out[(size_t)seg * 512 + 256 + col], sv);                \
                atomicMax((unsigned int*)&out[(size_t)seg * 512 + col],            \
                          __float_as_uint(mv));                                    \
            }                                                                      \
            accs[s] = 0.f; accm[s] = 0.f;                                          \
        }                                                                          \
    } while (0)

    // ---- prologue: stage chunk c0 into xl[0] ----
    {
        const float* src = x + (size_t)c0 * 64 * H;
#pragma unroll
        for (int i = 0; i < 2; ++i) {
            const int ch = tid + (i << 10);            // 0..2047, conflict-free layout
            const float4 lo = *(const float4*)(src + ch * 8);
            const float4 hi = *(const float4*)(src + ch * 8 + 4);
            bf16x8 v;
            v[0] = (short)f2bf(lo.x); v[1] = (short)f2bf(lo.y);
            v[2] = (short)f2bf(lo.z); v[3] = (short)f2bf(lo.w);
            v[4] = (short)f2bf(hi.x); v[5] = (short)f2bf(hi.y);
            v[6] = (short)f2bf(hi.z); v[7] = (short)f2bf(hi.w);
            *(bf16x8*)&xl[0][ch >> 5][(ch & 31) * 8] = v;
        }
    }
    __syncthreads();

    int cur = 0;
    for (int c = c0; c < c1; ++c) {
        const int rowbase = c * 64;
        const bool have_next = (c + 1 < c1);

        // ---- issue next chunk's x loads early (hide HBM under GEMM1) ----
        float4 st0, st1, st2, st3;
        if (have_next) {
            const float* src = x + (size_t)(c + 1) * 64 * H;
            const int ch0 = tid, ch1 = tid + 1024;
            st0 = *(const float4*)(src + ch0 * 8);
            st1 = *(const float4*)(src + ch0 * 8 + 4);
            st2 = *(const float4*)(src + ch1 * 8);
            st3 = *(const float4*)(src + ch1 * 8 + 4);
        }

        // ---- GEMM1: h-slice = relu(x @ W1^T + b1), cols [wave*16, +16) ----
        float hv[16];
        {
            bf16x8 w1f[8];
            const unsigned short* wrow = W1b + (size_t)col * H + q * 8;
#pragma unroll
            for (int kk = 0; kk < 8; ++kk)
                w1f[kk] = *(const bf16x8*)(wrow + kk * 32);
#pragma unroll
            for (int rg = 0; rg < 4; ++rg) {
                f32x4 a = (f32x4){0.f, 0.f, 0.f, 0.f};
#pragma unroll
                for (int kk = 0; kk < 8; ++kk) {
                    bf16x8 af = *(const bf16x8*)&xl[cur][rg * 16 + r][kk * 32 + q * 8];
                    a = __builtin_amdgcn_mfma_f32_16x16x32_bf16(af, w1f[kk], a, 0, 0, 0);
                }
#pragma unroll
                for (int e = 0; e < 4; ++e) {
                    float h = a[e] + bias1;
                    h = h > 0.f ? h : 0.f;
                    hv[rg * 4 + e] = h;                      // exact f32 for the gate
                    hl[rg * 16 + q * 4 + e][col] = (unsigned short)f2bf(h);
                }
            }
        }
        __syncthreads();   // hl ready; xl[cur] fully consumed

        // ---- write staged x to the other buffer (frees the regs early) ----
        if (have_next) {
            bf16x8 v;
            v[0] = (short)f2bf(st0.x); v[1] = (short)f2bf(st0.y);
            v[2] = (short)f2bf(st0.z); v[3] = (short)f2bf(st0.w);
            v[4] = (short)f2bf(st1.x); v[5] = (short)f2bf(st1.y);
            v[6] = (short)f2bf(st1.z); v[7] = (short)f2bf(st1.w);
            *(bf16x8*)&xl[cur ^ 1][tid >> 5][(tid & 31) * 8] = v;
            const int ch1 = tid + 1024;
            v[0] = (short)f2bf(st2.x); v[1] = (short)f2bf(st2.y);
            v[2] = (short)f2bf(st2.z); v[3] = (short)f2bf(st2.w);
            v[4] = (short)f2bf(st3.x); v[5] = (short)f2bf(st3.y);
            v[6] = (short)f2bf(st3.z); v[7] = (short)f2bf(st3.w);
            *(bf16x8*)&xl[cur ^ 1][ch1 >> 5][(ch1 & 31) * 8] = v;
        }

        // ---- GEMM2: att-slice, gate, segment reduction ----
        {
            bf16x8 w2f[8];
            const unsigned short* wrow = W2b + (size_t)col * H + q * 8;
#pragma unroll
            for (int kk = 0; kk < 8; ++kk)
                w2f[kk] = *(const bf16x8*)(wrow + kk * 32);
#pragma unroll
            for (int rg = 0; rg < 4; ++rg) {
                const int r0 = rowbase + rg * 16;

                if (wave == 0 && lane < 16)
                    atomicAdd(&counts[clampseg(batch[r0 + lane])], 1);

                // wave-uniform window maintenance (batch sorted)
                const int hi_seg = clampseg(batch[r0 + 15]);
                if (hi_seg - wb > 3) {
                    FLUSH_SLOTS();
                    wb = clampseg(batch[r0]);
                }

                f32x4 a = (f32x4){0.f, 0.f, 0.f, 0.f};
#pragma unroll
                for (int kk = 0; kk < 8; ++kk) {
                    bf16x8 af = *(const bf16x8*)&hl[rg * 16 + r][kk * 32 + q * 8];
                    a = __builtin_amdgcn_mfma_f32_16x16x32_bf16(af, w2f[kk], a, 0, 0, 0);
                }
#pragma unroll
                for (int e = 0; e < 4; ++e) {
                    float t   = a[e] + bias2;
                    float att = 1.f / (1.f + __expf(-t));
                    float gg  = hv[rg * 4 + e] * att;        // g >= 0
                    const int d = clampseg(batch[r0 + q * 4 + e]) - wb;
#pragma unroll
                    for (int s = 0; s < 4; ++s)
                        if (d == s) { accs[s] += gg; accm[s] = fmaxf(accm[s], gg); }
                    if (d < 0 || d > 3) {                    // out-of-window (rare)
                        const int seg = clampseg(wb + d);
                        atomicAdd(&out[(size_t)seg * 512 + 256 + col], gg);
                        atomicMax((unsigned int*)&out[(size_t)seg * 512 + col],
                                  __float_as_uint(gg));
                    }
                }
            }
        }
        __syncthreads();   // hl consumed by all; xl[cur^1] staged
        cur ^= 1;
    }

    FLUSH_SLOTS();
#undef FLUSH_SLOTS
}

__global__ void finalize_kernel(float* __restrict__ out, const int* __restrict__ counts) {
    const int b = blockIdx.x;
    const int c = threadIdx.x;
    const int cnt = counts[b];
    float s = out[(size_t)b * 512 + 256 + c];
    out[(size_t)b * 512 + 256 + c] = cnt > 0 ? s / (float)cnt : 0.0f;
}

extern "C" void kernel_launch(void* const* d_in, const int* in_sizes, int n_in,
                              void* d_out, int out_size, void* d_ws, size_t ws_size,
                              hipStream_t stream) {
    const float* x     = (const float*)d_in[0];
    const int*   batch = (const int*)d_in[1];
    const float* W1    = (const float*)d_in[2];
    const float* b1    = (const float*)d_in[3];
    const float* W2    = (const float*)d_in[4];
    const float* b2    = (const float*)d_in[5];
    float* out = (float*)d_out;

    unsigned short* W1b    = (unsigned short*)d_ws;
    unsigned short* W2b    = W1b + 65536;
    int*            counts = (int*)(W2b + 65536);

    const int Nrows   = in_sizes[0] / H;   // 200000
    const int nchunks = Nrows / 64;        // 3125 (exact)

    hipMemsetAsync(d_out, 0, (size_t)out_size * sizeof(float), stream);
    hipMemsetAsync(counts, 0, 512 * sizeof(int), stream);
    conv_w_kernel<<<256, 256, 0, stream>>>(W1, W2, W1b, W2b);
    fused_v5<<<256, 1024, 0, stream>>>(x, batch, W1b, b1, W2b, b2, out, counts, nchunks);
    finalize_kernel<<<512, 256, 0, stream>>>(out, counts);
}